// Round 19
// baseline (21.679 us; speedup 1.0000x reference)
//
#include <hip/hip_runtime.h>

#define HH 128
#define WW 192
#define HW (HH * WW)

typedef float f32x4 __attribute__((ext_vector_type(4)));
typedef float f32x2v __attribute__((ext_vector_type(2)));
typedef __fp16 h2 __attribute__((ext_vector_type(2)));

__device__ __forceinline__ float fdot2(h2 a, h2 b, float c) {
    return __builtin_amdgcn_fdot2(a, b, c, false);
}
__device__ __forceinline__ h2 pkrtz(float a, float b) {
    return __builtin_amdgcn_cvt_pkrtz(a, b);
}
__device__ __forceinline__ h2 prelu2(h2 v) {
    h2 z = {(__fp16)0.0f, (__fp16)0.0f};
    return __builtin_elementwise_max(v, z);
}

// LDS packed-weight layout:
//   sWp (h2): [0..31] w0feat o*4+p=(w0[o][2+2p],w0[o][3+2p])
//             [32..63] w1 32+o*4+p=(w1[o][2p],w1[o][2p+1])
//             [64..67] w2 64+p=(w2[2p],w2[2p+1])
//   sF (f32): [0..7] w0x [8..15] w0y [16..23] b0 [24..31] b1 [32] b2

__global__ __launch_bounds__(512) void dmh_kernel(
    const float* __restrict__ mask_feats,   // (4,8,128,192)
    const float* __restrict__ params,       // (128,169)
    const float* __restrict__ locs,         // (128,2)
    const float* __restrict__ soi,          // (5,)
    const int*   __restrict__ im_inds,      // (128,)
    const int*   __restrict__ fpn_levels,   // (128,)
    const int*   __restrict__ stride_p,     // scalar (=8)
    float*       __restrict__ out)          // (128,1,256,384)
{
    const int tid = threadIdx.x;
    const int c0 = blockIdx.x * 64;   // source col tile origin
    const int r0 = blockIdx.y * 32;   // source row tile origin
    const int n  = blockIdx.z;        // instance

    __shared__ h2    sWp[68];
    __shared__ float sF[33];
    __shared__ float tile[33 * 66];   // rows -1..31 -> 0..32, cols -1..63 -> 0..64

    // ---- stage weights: fp16-pack matmul weights, fp32 for coords/biases ----
    if (tid < 169) {
        float v = params[(size_t)n * 169 + tid];
        __fp16* sWh = reinterpret_cast<__fp16*>(sWp);
        if (tid < 80) {
            int o = tid / 10, k = tid - o * 10;
            if (k == 0)      sF[o] = v;
            else if (k == 1) sF[8 + o] = v;
            else { int f = k - 2; sWh[(o * 4 + (f >> 1)) * 2 + (f & 1)] = (__fp16)v; }
        } else if (tid < 144) {
            int t = tid - 80, o = t >> 3, i = t & 7;
            sWh[(32 + o * 4 + (i >> 1)) * 2 + (i & 1)] = (__fp16)v;
        } else if (tid < 152) {
            int o = tid - 144;
            sWh[(64 + (o >> 1)) * 2 + (o & 1)] = (__fp16)v;
        } else if (tid < 160) sF[16 + (tid - 152)] = v;   // b0
        else if (tid < 168)   sF[24 + (tid - 160)] = v;   // b1
        else                  sF[32] = v;                  // b2
    }

    const int   stride = *stride_p;                 // 8
    const float half_s = 0.5f * (float)stride;      // 4.0
    const float locx = locs[2 * n + 0];
    const float locy = locs[2 * n + 1];
    const float inv  = 1.0f / soi[fpn_levels[n]];
    const float* fb  = mask_feats + (size_t)im_inds[n] * 8 * HW;

    // ---- interior geometry: 1 row x 4 cols per thread ----
    const int ir = tid >> 4;          // 0..31
    const int ic = (tid & 15) << 2;   // 0,4,...,60
    const int rr = r0 + ir, cc = c0 + ic;
    const float* fp = fb + rr * WW + cc;

    // interior feat loads issued pre-barrier
    f32x4 xv[8];
    #pragma unroll
    for (int ch = 0; ch < 8; ++ch)
        xv[ch] = *reinterpret_cast<const f32x4*>(fp + ch * HW);

    // halo feat loads ALSO issued pre-barrier (threads 0..96)
    const bool isHalo = (tid < 97);
    int hTile = 0;
    float hx[8];
    float hrx = 0.0f, hry = 0.0f;
    if (isHalo) {
        int r, c;
        if (tid < 65) { r = -1; c = tid - 1; }      // row -1, cols -1..63
        else          { r = tid - 65; c = -1; }     // rows 0..31, col -1
        int hr = min(max(r0 + r, 0), HH - 1);
        int hc = min(max(c0 + c, 0), WW - 1);
        hTile = (r + 1) * 66 + (c + 1);
        const float* hfp = fb + hr * WW + hc;
        #pragma unroll
        for (int ch = 0; ch < 8; ++ch) hx[ch] = hfp[ch * HW];
        hrx = (locx - (float)(hc * stride) - half_s) * inv;
        hry = (locy - (float)(hr * stride) - half_s) * inv;
    }

    __syncthreads();

    // ---------- phase 1b FIRST: halo px MLP (overlaps other waves' interior) ----------
    if (isHalo) {
        h2 xp[4];
        #pragma unroll
        for (int p = 0; p < 4; ++p)
            xp[p] = pkrtz(hx[2 * p], hx[2 * p + 1]);
        float hh[8];
        #pragma unroll
        for (int o = 0; o < 8; ++o) {
            float acc = fmaf(sF[o], hrx, fmaf(sF[8 + o], hry, sF[16 + o]));
            #pragma unroll
            for (int p = 0; p < 4; ++p) acc = fdot2(sWp[o * 4 + p], xp[p], acc);
            hh[o] = acc;
        }
        h2 hp[4];
        #pragma unroll
        for (int p = 0; p < 4; ++p)
            hp[p] = prelu2(pkrtz(hh[2 * p], hh[2 * p + 1]));
        float aa[8];
        #pragma unroll
        for (int o = 0; o < 8; ++o) {
            float acc = sF[24 + o];
            #pragma unroll
            for (int p = 0; p < 4; ++p) acc = fdot2(sWp[32 + o * 4 + p], hp[p], acc);
            aa[o] = acc;
        }
        float lg = sF[32];
        #pragma unroll
        for (int p = 0; p < 4; ++p) {
            h2 ap = prelu2(pkrtz(aa[2 * p], aa[2 * p + 1]));
            lg = fdot2(sWp[64 + p], ap, lg);
        }
        tile[hTile] = lg;
    }

    // ---------- phase 1a: interior MLP via v_dot2_f32_f16 ----------
    {
        const float rxd = -(float)stride * inv;
        float rx[4];
        rx[0] = (locx - (float)(cc * stride) - half_s) * inv;
        rx[1] = rx[0] + rxd; rx[2] = rx[1] + rxd; rx[3] = rx[2] + rxd;
        const float ry = (locy - (float)(rr * stride) - half_s) * inv;

        h2 xp[4][4];
        #pragma unroll
        for (int p = 0; p < 4; ++p)
            #pragma unroll
            for (int j = 0; j < 4; ++j)
                xp[p][j] = pkrtz(xv[2 * p][j], xv[2 * p + 1][j]);

        float h[8][4];
        #pragma unroll
        for (int o = 0; o < 8; ++o) {
            const h2 w0 = sWp[o * 4 + 0], w1 = sWp[o * 4 + 1],
                     w2 = sWp[o * 4 + 2], w3 = sWp[o * 4 + 3];
            float tO = fmaf(sF[8 + o], ry, sF[16 + o]);
            float wx = sF[o];
            #pragma unroll
            for (int j = 0; j < 4; ++j) {
                float acc = fmaf(wx, rx[j], tO);
                acc = fdot2(w0, xp[0][j], acc);
                acc = fdot2(w1, xp[1][j], acc);
                acc = fdot2(w2, xp[2][j], acc);
                acc = fdot2(w3, xp[3][j], acc);
                h[o][j] = acc;
            }
        }

        h2 hp[4][4];
        #pragma unroll
        for (int p = 0; p < 4; ++p)
            #pragma unroll
            for (int j = 0; j < 4; ++j)
                hp[p][j] = prelu2(pkrtz(h[2 * p][j], h[2 * p + 1][j]));

        float a[8][4];
        #pragma unroll
        for (int o = 0; o < 8; ++o) {
            const h2 w0 = sWp[32 + o * 4 + 0], w1 = sWp[32 + o * 4 + 1],
                     w2 = sWp[32 + o * 4 + 2], w3 = sWp[32 + o * 4 + 3];
            float b1 = sF[24 + o];
            #pragma unroll
            for (int j = 0; j < 4; ++j) {
                float acc = b1;
                acc = fdot2(w0, hp[0][j], acc);
                acc = fdot2(w1, hp[1][j], acc);
                acc = fdot2(w2, hp[2][j], acc);
                acc = fdot2(w3, hp[3][j], acc);
                a[o][j] = acc;
            }
        }

        const h2 v0 = sWp[64], v1 = sWp[65], v2 = sWp[66], v3 = sWp[67];
        const float b2v = sF[32];
        #pragma unroll
        for (int j = 0; j < 4; ++j) {
            h2 a0 = prelu2(pkrtz(a[0][j], a[1][j]));
            h2 a1 = prelu2(pkrtz(a[2][j], a[3][j]));
            h2 a2 = prelu2(pkrtz(a[4][j], a[5][j]));
            h2 a3 = prelu2(pkrtz(a[6][j], a[7][j]));
            float lg = b2v;
            lg = fdot2(v0, a0, lg);
            lg = fdot2(v1, a1, lg);
            lg = fdot2(v2, a2, lg);
            lg = fdot2(v3, a3, lg);
            tile[(ir + 1) * 66 + ic + 1 + j] = lg;
        }
    }
    __syncthreads();

    // ---------- phase 2: x2 upsample, dual-row emission ----------
    // wave wv owns tile-row pairs; each iter reads rows k,k+1 ONCE and emits
    // out rows 2k+1 (copy of row k... actually row k+? see mapping) and 2k+2
    // (average). Mapping: out y odd (y=2m+1) = src row m; y even (y=2m+2) =
    // avg(src m, m+1); y=0 = src row 0 (handled by iter k=0 via row -1 clamp
    // already in tile row 0 == src r0-1 clamped... we emit y=2k and y=2k+1
    // from tile rows k, k+1: y=2k   -> iy=2k-1 -> rb=k-1, fy=1 -> avg(k-1+1=k? )
    // Derivation: local out row yt in [0,64): iy=yt-1, sr=(iy>>1)+1, fy=iy&1.
    //   yt=2k   (k>=0): iy=2k-1, sr=k (k>=1) or arith k=0-> sr=0... fy=1 -> avg(sr, sr+1)=avg(k,k+1); yt=0: iy=-1, sr=0, fy=1 -> avg(row0,row1)?? iy=-1: iy>>1=-1 -> sr=0, fy= (-1)&1=1 -> avg(0,1) WRONG for y=0?
    //   Actually global y=2*r0+yt; for r0=0,yt=0: y=0 -> out row 0 = src row 0
    //   (edge pad). tile row 0 = clamped src r0-1 = src row 0, tile row 1 =
    //   src row 0?? no: tile row 1 = src r0+0. For r0=0: tile row 0 = clamp(-1)=0
    //   = src 0, row 1 = src 0?? NO row 1 = src r0 = 0. Both = src row 0 -> avg
    //   = src row 0. CORRECT. General yt=2k: avg(tile k, tile k+1) where tile k
    //   = src r0+k-1: avg(src r0+k-1, r0+k) ✓ (y=2(r0+k), m=(y-2)/2+? y even:
    //   y=2m+2 -> m=r0+k-1 ✓ avg(m, m+1) ✓).
    //   yt=2k+1: iy=2k, sr=k+1, fy=0 -> copy tile k+1 = src r0+k ✓ (y=2m+1,
    //   m=r0+k ✓).
    // So iter k (0..31): read tile rows k, k+1 -> emit yt=2k (avg), yt=2k+1 (copy).
    {
        const int lane = tid & 63;
        const int wv   = tid >> 6;        // 0..7 -> iters k = wv*4 .. wv*4+3
        float* ob = out + ((size_t)n * 256 + 2 * r0) * 384 + 2 * c0 + 2 * lane;
        #pragma unroll
        for (int i = 0; i < 4; ++i) {
            int k = wv * 4 + i;           // 0..31
            const float* ta = &tile[k * 66 + lane];        // row k
            const float* tb = ta + 66;                      // row k+1
            float a0 = ta[0], a1 = ta[1];
            float b0 = tb[0], b1 = tb[1];
            // yt = 2k: avg rows
            float e0 = 0.5f * (a0 + b0);
            float e1 = 0.5f * (a1 + b1);
            f32x2v oE = {0.5f * (e0 + e1), e1};
            __builtin_nontemporal_store(oE,
                reinterpret_cast<f32x2v*>(ob + (size_t)(2 * k) * 384));
            // yt = 2k+1: copy row k+1
            f32x2v oO = {0.5f * (b0 + b1), b1};
            __builtin_nontemporal_store(oO,
                reinterpret_cast<f32x2v*>(ob + (size_t)(2 * k + 1) * 384));
        }
    }
}

extern "C" void kernel_launch(void* const* d_in, const int* in_sizes, int n_in,
                              void* d_out, int out_size, void* d_ws, size_t ws_size,
                              hipStream_t stream) {
    const float* mask_feats = (const float*)d_in[0];
    const float* params     = (const float*)d_in[1];
    const float* locs       = (const float*)d_in[2];
    const float* soi        = (const float*)d_in[3];
    const int*   im_inds    = (const int*)d_in[4];
    const int*   fpn_levels = (const int*)d_in[5];
    const int*   stride_p   = (const int*)d_in[6];
    float* out = (float*)d_out;

    dim3 grid(WW / 64, HH / 32, 128);   // (3, 4, 128)
    dim3 block(512);
    dmh_kernel<<<grid, block, 0, stream>>>(
        mask_feats, params, locs, soi, im_inds, fpn_levels, stride_p, out);
}